// Round 13
// baseline (379.542 us; speedup 1.0000x reference)
//
#include <hip/hip_runtime.h>

typedef __attribute__((ext_vector_type(8))) short s16x8;   // bf16x8 MFMA operand
typedef __attribute__((ext_vector_type(4))) float f32x4;   // MFMA accumulator

constexpr int kNC = 100000;
constexpr int kNP = 50000;
constexpr int kNT = kNC + kNP;
constexpr int kE1 = 300000;
constexpr int kE2 = 300000;
constexpr int kCAP = 32;   // max in-degree per node per edge type

__device__ __forceinline__ float geluf(float x) {
    return 0.5f * x * (1.0f + erff(x * 0.7071067811865475f));
}
__device__ __forceinline__ unsigned short f2bf(float f) {  // RTNE
    unsigned int u = __float_as_uint(f);
    u += 0x7fffu + ((u >> 16) & 1u);
    return (unsigned short)(u >> 16);
}
__device__ __forceinline__ float bf2f(unsigned short s) {
    return __uint_as_float(((unsigned int)s) << 16);
}
// packed-bf16 word -> two floats (hi is free: just mask; lo: shift)
__device__ __forceinline__ float bfLo(unsigned int w) { return __uint_as_float(w << 16); }
__device__ __forceinline__ float bfHi(unsigned int w) { return __uint_as_float(w & 0xffff0000u); }

// 16-lane rotate-reduce on the VALU pipe (DPP row_ror), ~4cy/step vs ~30cy ds_swizzle.
// After ror 1,2,4,8 every lane in each 16-lane row holds the row sum (ulp-order varies per lane).
__device__ __forceinline__ float rowSum16(float s) {
    s += __int_as_float(__builtin_amdgcn_mov_dpp(__float_as_int(s), 0x121, 0xf, 0xf, false)); // row_ror:1
    s += __int_as_float(__builtin_amdgcn_mov_dpp(__float_as_int(s), 0x122, 0xf, 0xf, false)); // row_ror:2
    s += __int_as_float(__builtin_amdgcn_mov_dpp(__float_as_int(s), 0x124, 0xf, 0xf, false)); // row_ror:4
    s += __int_as_float(__builtin_amdgcn_mov_dpp(__float_as_int(s), 0x128, 0xf, 0xf, false)); // row_ror:8
    return s;
}

// f32 -> bf16 elementwise (8 elems/thread, vectorized)
__global__ __launch_bounds__(256) void cvt_bf16(
    const float* __restrict__ in, unsigned short* __restrict__ out, int n8)
{
    int i = blockIdx.x * 256 + threadIdx.x;
    if (i >= n8) return;
    float4 a = *(const float4*)(in + (size_t)i * 8);
    float4 b = *(const float4*)(in + (size_t)i * 8 + 4);
    ushort4 o0 = { f2bf(a.x), f2bf(a.y), f2bf(a.z), f2bf(a.w) };
    ushort4 o1 = { f2bf(b.x), f2bf(b.y), f2bf(b.z), f2bf(b.w) };
    *(ushort4*)(out + (size_t)i * 8) = o0;
    *(ushort4*)(out + (size_t)i * 8 + 4) = o1;
}

// W [128 rows k][ncols] (row stride ldb, f32) -> WT bf16 [col][128 k]
__global__ __launch_bounds__(128) void cvt_wT(
    const float* __restrict__ src, int ldb, unsigned short* __restrict__ dst)
{
    int c = blockIdx.x;
    int r = threadIdx.x;    // 0..127 (k)
    dst[(size_t)c * 128 + r] = f2bf(src[(size_t)r * ldb + c]);
}

// Folded kqv weights, bf16 TRANSPOSED out: wt[col][k] = (w @ blockdiag-fold)[k][col]
__global__ void fold_k(const float* __restrict__ w, const float* __restrict__ b,
                       const float* __restrict__ ar, const float* __restrict__ mr,
                       unsigned short* __restrict__ wt, float* __restrict__ beff) {
    int col = blockIdx.x;   // 0..383
    int i = threadIdx.x;    // 0..127 (k-row)
    float acc, bacc;
    if (col >= 128 && col < 256) {
        acc = w[i * 384 + col];
        bacc = b[col];
    } else {
        const float* rel = (col < 128) ? ar : mr;
        int base = (col < 128) ? 0 : 256;
        int c = col - base;
        int h = c >> 6, j = c & 63;
        acc = 0.0f; bacc = 0.0f;
        for (int d = 0; d < 64; ++d) {
            float rv = rel[(h * 64 + d) * 64 + j];
            acc  = fmaf(w[i * 384 + base + h * 64 + d], rv, acc);
            bacc = fmaf(b[base + h * 64 + d], rv, bacc);
        }
    }
    wt[(size_t)col * 128 + i] = f2bf(acc);
    if (i == 0) beff[col] = bacc;
}

struct Job {
    const unsigned short* WT;    // bf16 [128 cols][128 k] (pre-transposed)
    const float* bias;           // pre-offset, 128 window, f32
    const unsigned short* A;     // bf16 [M,128]
    const unsigned short* Xres;  // residual bf16 (EPI)
    const float* sgate;          // gate scalar (EPI)
    void* out;                   // [M,128] bf16 (opt. kv-interleaved) or [M,16] f32 (FINAL)
    int M;
    int omap;                    // 1: kv-interleaved [node][256]: c -> 8*(c>>2)+(c&3)+roleOff
    int roleOff;                 // 0 for k, 4 for v
};

// C[M,128] = op(A) @ WT^T + bias via bf16 MFMA. 64-row blocks (latency-bound regime, R10/R11).
// All operands pre-bf16 -> staging is pure copy. PRO: gelu(A). EPI: g*o+(1-g)*Xres (+RELU).
// FINAL: fused @wlT+bl -> out [M,16] f32.
// Frag layout (gfx950 16x16x32, HW-verified R4-R6): A/B lane&15=row/col, k=(lane>>4)*4+(e&3)+16*(e>>2);
// C/D row=(lane>>4)*4+reg, col=lane&15.
template<int PRO, int EPI, int RELU, int FINAL>
__global__ __launch_bounds__(256) void gemm64(
    Job j0, Job j1, Job j2, Job j3, Job j4, Job j5,
    const unsigned short* __restrict__ wlt, const float* __restrict__ blv)
{
    Job J;
    switch (blockIdx.y) {
        case 0: J = j0; break;
        case 1: J = j1; break;
        case 2: J = j2; break;
        case 3: J = j3; break;
        case 4: J = j4; break;
        default: J = j5; break;
    }
    const int row0 = blockIdx.x * 64;
    const int M = J.M;
    if (row0 >= M) return;

    constexpr int NSM = FINAL ? (64 * 132) : (64 * 36 + 128 * 36);
    __shared__ unsigned short sm[NSM];
    unsigned short* As = sm;               // [64][36]
    unsigned short* Bs = sm + 64 * 36;     // [128][36]

    const int t = threadIdx.x;
    const int lane = t & 63;
    const int w = t >> 6;
    const int l15 = lane & 15, l4 = lane >> 4;

    f32x4 acc[8];
    #pragma unroll
    for (int n = 0; n < 8; ++n) {
        float bv = J.bias[n * 16 + l15];
        acc[n] = f32x4{bv, bv, bv, bv};
    }

    union FR { uint2 u[2]; s16x8 v; };

    for (int kc = 0; kc < 4; ++kc) {
        const int k0 = kc * 32;
        ushort4 a_[2];
        #pragma unroll
        for (int i = 0; i < 2; ++i) {
            int idx = i * 256 + t;
            int r = idx >> 3, kq = idx & 7;
            int gr = row0 + r;
            ushort4 rv = {0, 0, 0, 0};
            if (gr < M) rv = *(const ushort4*)(J.A + (size_t)gr * 128 + k0 + kq * 4);
            if (PRO) {
                rv.x = f2bf(geluf(bf2f(rv.x)));
                rv.y = f2bf(geluf(bf2f(rv.y)));
                rv.z = f2bf(geluf(bf2f(rv.z)));
                rv.w = f2bf(geluf(bf2f(rv.w)));
            }
            a_[i] = rv;
        }
        ushort4 b_[4];
        #pragma unroll
        for (int i = 0; i < 4; ++i) {
            int idx = i * 256 + t;
            int c = idx >> 3, kq = idx & 7;
            b_[i] = *(const ushort4*)(J.WT + (size_t)c * 128 + k0 + kq * 4);
        }
        if (kc) __syncthreads();
        #pragma unroll
        for (int i = 0; i < 2; ++i) {
            int idx = i * 256 + t;
            int r = idx >> 3, kq = idx & 7;
            *(ushort4*)&As[r * 36 + kq * 4] = a_[i];
        }
        #pragma unroll
        for (int i = 0; i < 4; ++i) {
            int idx = i * 256 + t;
            int c = idx >> 3, kq = idx & 7;
            *(ushort4*)&Bs[c * 36 + kq * 4] = b_[i];
        }
        __syncthreads();

        FR af;
        {
            const unsigned short* p = &As[(w * 16 + l15) * 36 + l4 * 4];
            af.u[0] = *(const uint2*)p;
            af.u[1] = *(const uint2*)(p + 16);
        }
        #pragma unroll
        for (int n = 0; n < 8; ++n) {
            const unsigned short* p = &Bs[(n * 16 + l15) * 36 + l4 * 4];
            FR bfr;
            bfr.u[0] = *(const uint2*)p;
            bfr.u[1] = *(const uint2*)(p + 16);
            acc[n] = __builtin_amdgcn_mfma_f32_16x16x32_bf16(af.v, bfr.v, acc[n], 0, 0, 0);
        }
    }

    float g = 0.f, omg = 0.f;
    if (EPI == 1) { g = 1.0f / (1.0f + expf(-J.sgate[0])); omg = 1.0f - g; }

    if (FINAL) __syncthreads();   // all frag reads done before tile overwrites sm

    #pragma unroll
    for (int r = 0; r < 4; ++r) {
        int lr = w * 16 + l4 * 4 + r;
        int gr = row0 + lr;
        bool ok = gr < M;
        #pragma unroll
        for (int n = 0; n < 8; ++n) {
            float v = acc[n][r];
            if (EPI == 1) {
                float xv = ok ? bf2f(J.Xres[(size_t)gr * 128 + n * 16 + l15]) : 0.f;
                v = g * v + omg * xv;
                if (RELU) v = fmaxf(v, 0.0f);
            }
            if (FINAL) {
                sm[lr * 132 + n * 16 + l15] = f2bf(v);
            } else if (ok) {
                unsigned short hv = f2bf(v);
                int c = n * 16 + l15;
                if (J.omap)
                    ((unsigned short*)J.out)[(size_t)gr * 256 + ((c >> 2) << 3) + (c & 3) + J.roleOff] = hv;
                else
                    ((unsigned short*)J.out)[(size_t)gr * 128 + c] = hv;
            }
        }
    }

    if (FINAL) {
        // per-wave rows [w*16, w*16+16) @ wlT[16][128] + bl (same-wave LDS RAW; no barrier)
        f32x4 facc;
        float bv = blv[l15];
        facc = f32x4{bv, bv, bv, bv};
        #pragma unroll
        for (int kc2 = 0; kc2 < 4; ++kc2) {
            FR bfr, afr;
            #pragma unroll
            for (int h = 0; h < 2; ++h) {
                bfr.u[h] = *(const uint2*)&wlt[(size_t)l15 * 128 + kc2 * 32 + h * 16 + l4 * 4];
                afr.u[h] = *(const uint2*)&sm[(w * 16 + l15) * 132 + kc2 * 32 + h * 16 + l4 * 4];
            }
            facc = __builtin_amdgcn_mfma_f32_16x16x32_bf16(afr.v, bfr.v, facc, 0, 0, 0);
        }
        #pragma unroll
        for (int r = 0; r < 4; ++r) {
            int gr = row0 + w * 16 + l4 * 4 + r;
            if (gr < M) ((float*)J.out)[(size_t)gr * 16 + l15] = facc[r];
        }
    }
}

// per edge: slot = cnt[dst]++; bucket[dst*CAP+slot] = src
__global__ __launch_bounds__(256) void build_bucket(
    const int* __restrict__ src, const int* __restrict__ dst, int E,
    int* __restrict__ cnt, int* __restrict__ bucket)
{
    int e = blockIdx.x * 256 + threadIdx.x;
    if (e >= E) return;
    int d = dst[e];
    int slot = atomicAdd(&cnt[d], 1);
    if (slot < kCAP) bucket[(size_t)d * kCAP + slot] = src[e];
}

// Max-free single-pass segment softmax, TWO edges per wave iteration:
// lanes 0-31 process edge 2i, lanes 32-63 edge 2i+1. lane&31 owns 4 row elems.
// Per-head (16-lane) reduce now on the VALU pipe via DPP rotate (rowSum16) — no LDS-pipe
// ops in the loop; edge pair indices read directly from bucket (uniform int2 load, no bpermute).
// kv row groups-of-4 interleave -> one 16B load per lane per edge-pair.
__global__ __launch_bounds__(256) void fused_attn2(
    int nA, const int* __restrict__ cntA, const int* __restrict__ bucketA,
    const unsigned short* __restrict__ kvA, unsigned short* __restrict__ qoA,
    const float* __restrict__ prelA,
    int nB, const int* __restrict__ cntB, const int* __restrict__ bucketB,
    const unsigned short* __restrict__ kvB, unsigned short* __restrict__ qoB,
    const float* __restrict__ prelB)
{
    int wid = (blockIdx.x * 256 + threadIdx.x) >> 6;
    int lane = threadIdx.x & 63;
    const int* cnt; const int* bucket; const unsigned short* kvs;
    unsigned short* qo; const float* prel;
    if (wid < nA) {
        cnt = cntA; bucket = bucketA; kvs = kvA; qo = qoA; prel = prelA;
    } else {
        wid -= nA;
        if (wid >= nB) return;
        cnt = cntB; bucket = bucketB; kvs = kvB; qo = qoB; prel = prelB;
    }
    int deg = cnt[wid];
    if (deg > kCAP) deg = kCAP;
    const int l31 = lane & 31;
    uint2 qv = *(const uint2*)(qo + (size_t)wid * 128 + l31 * 4);
    float q0 = bfLo(qv.x), q1 = bfHi(qv.x), q2 = bfLo(qv.y), q3 = bfHi(qv.y);
    float ph = prel[l31 >> 4] * 0.125f;   // / sqrt(64)

    float ss = 0.f, o0 = 0.f, o1 = 0.f, o2 = 0.f, o3 = 0.f;
    const int half = lane >> 5;     // 0: even edges, 1: odd edges
    const int nIt = (deg + 1) >> 1;
    const int* bp = bucket + (size_t)wid * kCAP;
    for (int i = 0; i < nIt; ++i) {
        int2 sp = *(const int2*)(bp + 2 * i);    // wave-uniform 8B load
        int idx = 2 * i + half;
        bool valid = idx < deg;
        int s = half ? sp.y : sp.x;
        if (!valid) s = 0;                        // bucket tail is poison; clamp address
        uint4 kv = *(const uint4*)(kvs + (size_t)s * 256 + l31 * 8);
        float p = q0 * bfLo(kv.x) + q1 * bfHi(kv.x) + q2 * bfLo(kv.y) + q3 * bfHi(kv.y);
        p = rowSum16(p);                          // per-head sum, VALU-only
        float wgt = valid ? __expf(p * ph) : 0.f;
        ss += wgt;
        o0 = fmaf(wgt, bfLo(kv.z), o0);
        o1 = fmaf(wgt, bfHi(kv.z), o1);
        o2 = fmaf(wgt, bfLo(kv.w), o2);
        o3 = fmaf(wgt, bfHi(kv.w), o3);
    }
    // merge even/odd partials across the two 32-lane halves
    ss += __shfl_xor(ss, 32);
    o0 += __shfl_xor(o0, 32);
    o1 += __shfl_xor(o1, 32);
    o2 += __shfl_xor(o2, 32);
    o3 += __shfl_xor(o3, 32);
    float rr = 1.0f / (ss + 1e-16f);
    if (lane < 32) {
        uint2 ov;
        ov.x = (unsigned)f2bf(o0 * rr) | ((unsigned)f2bf(o1 * rr) << 16);
        ov.y = (unsigned)f2bf(o2 * rr) | ((unsigned)f2bf(o3 * rr) << 16);
        *(uint2*)(qo + (size_t)wid * 128 + l31 * 4) = ov;
    }
}

extern "C" void kernel_launch(void* const* d_in, const int* in_sizes, int n_in,
                              void* d_out, int out_size, void* d_ws, size_t ws_size,
                              hipStream_t stream)
{
    const float* xc  = (const float*)d_in[0];
    const float* xp  = (const float*)d_in[1];
    const float* w1c = (const float*)d_in[2];
    const float* b1c = (const float*)d_in[3];
    const float* w1p = (const float*)d_in[4];
    const float* b1p = (const float*)d_in[5];
    const float* a1cp= (const float*)d_in[6];
    const float* m1cp= (const float*)d_in[7];
    const float* p1cp= (const float*)d_in[8];
    const float* a1pc= (const float*)d_in[9];
    const float* m1pc= (const float*)d_in[10];
    const float* p1pc= (const float*)d_in[11];
    const float* ow1c= (const float*)d_in[12];
    const float* ob1c= (const float*)d_in[13];
    const float* ow1p= (const float*)d_in[14];
    const float* ob1p= (const float*)d_in[15];
    const float* s1c = (const float*)d_in[16];
    const float* s1p = (const float*)d_in[17];
    const float* w2c = (const float*)d_in[18];
    const float* b2c = (const float*)d_in[19];
    const float* w2p = (const float*)d_in[20];
    const float* b2p = (const float*)d_in[21];
    const float* a2pc= (const float*)d_in[25];
    const float* m2pc= (const float*)d_in[26];
    const float* p2pc= (const float*)d_in[27];
    const float* ow2c= (const float*)d_in[28];
    const float* ob2c= (const float*)d_in[29];
    const float* s2c = (const float*)d_in[32];
    const float* wl  = (const float*)d_in[34];
    const float* bl  = (const float*)d_in[35];
    const int* ecp_s = (const int*)d_in[36];
    const int* ecp_d = (const int*)d_in[37];
    const int* epc_s = (const int*)d_in[38];
    const int* epc_d = (const int*)d_in[39];
    float* outF = (float*)d_out;
    (void)in_sizes; (void)n_in; (void)out_size; (void)ws_size;

    // ---- workspace layout (~188 MB) ----
    char* ws = (char*)d_ws;
    size_t off = 0;
    auto take = [&](size_t bytes) { char* p = ws + off; off += (bytes + 255) & ~(size_t)255; return p; };
    // R0: kvC interleaved bf16 [NC][256] (L1) -> hcb bf16 [NC][128] (from mix1 to end)
    char* R0 = take((size_t)kNC * 256 * 2);
    unsigned short* kvC = (unsigned short*)R0;
    unsigned short* hcb = (unsigned short*)R0;
    // R1: kvP interleaved bf16 [NP][256] (L1) -> reused for L2
    unsigned short* kvP = (unsigned short*)take((size_t)kNP * 256 * 2);
    // R2: q/attn-out bf16 [NT][128]
    unsigned short* qAll = (unsigned short*)take((size_t)kNT * 128 * 2);
    unsigned short* qC = qAll;
    unsigned short* qP = qAll + (size_t)kNC * 128;
    // R3: hp bf16
    unsigned short* hp = (unsigned short*)take((size_t)kNP * 128 * 2);
    // R4: buckets
    int* cntP = (int*)take((size_t)kNP * 4);
    int* cntC = (int*)take((size_t)kNC * 4);
    int* bucketP = (int*)take((size_t)kNP * kCAP * 4);
    int* bucketC = (int*)take((size_t)kNC * kCAP * 4);
    // R5: folded/converted weights, bf16 transposed [col][128]
    unsigned short* wecT = (unsigned short*)take((size_t)384 * 128 * 2);
    unsigned short* wepT = (unsigned short*)take((size_t)384 * 128 * 2);
    unsigned short* ow1cT= (unsigned short*)take((size_t)128 * 128 * 2);
    unsigned short* ow1pT= (unsigned short*)take((size_t)128 * 128 * 2);
    unsigned short* ow2cT= (unsigned short*)take((size_t)128 * 128 * 2);
    unsigned short* w2cqT= (unsigned short*)take((size_t)128 * 128 * 2);
    unsigned short* wlT  = (unsigned short*)take((size_t)16 * 128 * 2);
    float* bec = (float*)take((size_t)384 * 4);
    float* bep = (float*)take((size_t)384 * 4);
    // R6: bf16 copies of inputs
    unsigned short* xcb = (unsigned short*)take((size_t)kNC * 128 * 2);
    unsigned short* xpb = (unsigned short*)take((size_t)kNP * 128 * 2);

    auto cdiv = [](int a, int b) { return (a + b - 1) / b; };
    dim3 blk(256);
    const int gx = cdiv(kNC, 64);   // 1563
    const float* nf = nullptr;
    const unsigned short* nu = nullptr;

    // buckets (same edge lists both layers)
    hipMemsetAsync(cntP, 0, (size_t)kNP * 4, stream);
    hipMemsetAsync(cntC, 0, (size_t)kNC * 4, stream);
    hipLaunchKernelGGL(build_bucket, dim3(cdiv(kE1, 256)), blk, 0, stream, ecp_s, ecp_d, kE1, cntP, bucketP);
    hipLaunchKernelGGL(build_bucket, dim3(cdiv(kE2, 256)), blk, 0, stream, epc_s, epc_d, kE2, cntC, bucketC);

    // bf16 input copies + weight conversions (once)
    hipLaunchKernelGGL(cvt_bf16, dim3(cdiv(kNC * 16, 256)), blk, 0, stream, xc, xcb, kNC * 16);
    hipLaunchKernelGGL(cvt_bf16, dim3(cdiv(kNP * 16, 256)), blk, 0, stream, xp, xpb, kNP * 16);
    hipLaunchKernelGGL(cvt_wT, dim3(128), dim3(128), 0, stream, ow1c, 128, ow1cT);
    hipLaunchKernelGGL(cvt_wT, dim3(128), dim3(128), 0, stream, ow1p, 128, ow1pT);
    hipLaunchKernelGGL(cvt_wT, dim3(128), dim3(128), 0, stream, ow2c, 128, ow2cT);
    hipLaunchKernelGGL(cvt_wT, dim3(128), dim3(128), 0, stream, w2c + 128, 384, w2cqT);
    hipLaunchKernelGGL(cvt_wT, dim3(16),  dim3(128), 0, stream, wl, 16, wlT);

    // ================= layer 1 =================
    hipLaunchKernelGGL(fold_k, dim3(384), dim3(128), 0, stream, w1c, b1c, a1cp, m1cp, wecT, bec);
    hipLaunchKernelGGL(fold_k, dim3(384), dim3(128), 0, stream, w1p, b1p, a1pc, m1pc, wepT, bep);

    Job jkC = { wecT + 0,       bec + 0,   xcb, nu, nf, (void*)kvC, kNC, 1, 0 };
    Job jqC = { wecT + 128*128, bec + 128, xcb, nu, nf, (void*)qC,  kNC, 0, 0 };
    Job jvC = { wecT + 256*128, bec + 256, xcb, nu, nf, (void*)kvC, kNC, 1, 4 };
    Job jkP = { wepT + 0,       bep + 0,   xpb, nu, nf, (void*)kvP, kNP, 1, 0 };
    Job jqP = { wepT + 128*128, bep + 128, xpb, nu, nf, (void*)qP,  kNP, 0, 0 };
    Job jvP = { wepT + 256*128, bep + 256, xpb, nu, nf, (void*)kvP, kNP, 1, 4 };
    hipLaunchKernelGGL((gemm64<0,0,0,0>), dim3(gx, 6), blk, 0, stream,
                       jkC, jqC, jvC, jkP, jqP, jvP, nu, nf);

    // both L1 attentions in one dispatch (reads q bf16, overwrites with out bf16)
    hipLaunchKernelGGL(fused_attn2, dim3(cdiv(kNP + kNC, 4)), blk, 0, stream,
                       kNP, cntP, bucketP, kvC, qP, p1cp,
                       kNC, cntC, bucketC, kvP, qC, p1pc);

    Job jmC = { ow1cT, ob1c, qC, xcb, s1c, (void*)hcb, kNC, 0, 0 };
    Job jmP = { ow1pT, ob1p, qP, xpb, s1p, (void*)hp,  kNP, 0, 0 };
    hipLaunchKernelGGL((gemm64<1,1,1,0>), dim3(gx, 2), blk, 0, stream,
                       jmC, jmP, jmC, jmC, jmC, jmC, nu, nf);

    // ================= layer 2 (customer outputs only -> pc edges only) =================
    hipLaunchKernelGGL(fold_k, dim3(384), dim3(128), 0, stream, w2p, b2p, a2pc, m2pc, wepT, bep);
    Job jk2 = { wepT + 0,       bep + 0,   hp,  nu, nf, (void*)kvP, kNP, 1, 0 };
    Job jv2 = { wepT + 256*128, bep + 256, hp,  nu, nf, (void*)kvP, kNP, 1, 4 };
    Job jq2 = { w2cqT,          b2c + 128, hcb, nu, nf, (void*)qC,  kNC, 0, 0 };
    hipLaunchKernelGGL((gemm64<0,0,0,0>), dim3(gx, 3), blk, 0, stream,
                       jk2, jv2, jq2, jk2, jk2, jk2, nu, nf);

    hipLaunchKernelGGL(fused_attn2, dim3(cdiv(kNC, 4)), blk, 0, stream,
                       kNC, cntC, bucketC, kvP, qC, p2pc,
                       0, cntC, bucketC, kvP, qC, p2pc);

    // mix2 + final projection fused: writes d_out [NC,16] directly
    Job jf = { ow2cT, ob2c, qC, hcb, s2c, (void*)outF, kNC, 0, 0 };
    hipLaunchKernelGGL((gemm64<1,1,0,1>), dim3(gx, 1), blk, 0, stream,
                       jf, jf, jf, jf, jf, jf, wlT, bl);
}

// Round 14
// 357.384 us; speedup vs baseline: 1.0620x; 1.0620x over previous
//
#include <hip/hip_runtime.h>

typedef __attribute__((ext_vector_type(8))) short s16x8;   // bf16x8 MFMA operand
typedef __attribute__((ext_vector_type(4))) float f32x4;   // MFMA accumulator

constexpr int kNC = 100000;
constexpr int kNP = 50000;
constexpr int kNT = kNC + kNP;
constexpr int kE1 = 300000;
constexpr int kE2 = 300000;
constexpr int kCAP = 32;   // max in-degree per node per edge type

__device__ __forceinline__ float geluf(float x) {
    return 0.5f * x * (1.0f + erff(x * 0.7071067811865475f));
}
__device__ __forceinline__ unsigned short f2bf(float f) {  // RTNE
    unsigned int u = __float_as_uint(f);
    u += 0x7fffu + ((u >> 16) & 1u);
    return (unsigned short)(u >> 16);
}
__device__ __forceinline__ float bf2f(unsigned short s) {
    return __uint_as_float(((unsigned int)s) << 16);
}
// packed-bf16 word -> two floats (hi is free: just mask; lo: shift)
__device__ __forceinline__ float bfLo(unsigned int w) { return __uint_as_float(w << 16); }
__device__ __forceinline__ float bfHi(unsigned int w) { return __uint_as_float(w & 0xffff0000u); }

// f32 -> bf16 elementwise (8 elems/thread, vectorized)
__global__ __launch_bounds__(256) void cvt_bf16(
    const float* __restrict__ in, unsigned short* __restrict__ out, int n8)
{
    int i = blockIdx.x * 256 + threadIdx.x;
    if (i >= n8) return;
    float4 a = *(const float4*)(in + (size_t)i * 8);
    float4 b = *(const float4*)(in + (size_t)i * 8 + 4);
    ushort4 o0 = { f2bf(a.x), f2bf(a.y), f2bf(a.z), f2bf(a.w) };
    ushort4 o1 = { f2bf(b.x), f2bf(b.y), f2bf(b.z), f2bf(b.w) };
    *(ushort4*)(out + (size_t)i * 8) = o0;
    *(ushort4*)(out + (size_t)i * 8 + 4) = o1;
}

// 5 W->WT bf16 transpose-converts in ONE dispatch (grid 528; saves 4 serial launches)
__global__ __launch_bounds__(128) void cvt_wT5(
    const float* __restrict__ s0, const float* __restrict__ s1,
    const float* __restrict__ s2, const float* __restrict__ s3,
    const float* __restrict__ s4,
    unsigned short* __restrict__ d0, unsigned short* __restrict__ d1,
    unsigned short* __restrict__ d2, unsigned short* __restrict__ d3,
    unsigned short* __restrict__ d4)
{
    int b = blockIdx.x;
    const float* src; unsigned short* dst; int ldb; int c;
    if (b < 128)      { src = s0; dst = d0; ldb = 128; c = b; }
    else if (b < 256) { src = s1; dst = d1; ldb = 128; c = b - 128; }
    else if (b < 384) { src = s2; dst = d2; ldb = 128; c = b - 256; }
    else if (b < 512) { src = s3; dst = d3; ldb = 384; c = b - 384; }
    else              { src = s4; dst = d4; ldb = 16;  c = b - 512; }
    int r = threadIdx.x;    // 0..127 (k)
    dst[(size_t)c * 128 + r] = f2bf(src[(size_t)r * ldb + c]);
}

// All three kqv weight folds in ONE dispatch (grid 1152). Job j = blockIdx.x/384.
// wt[col][k] bf16 transposed; L2 fold writes its own wep2T (no WAR on wepT).
__global__ void fold_all(
    const float* __restrict__ wA, const float* __restrict__ bA,
    const float* __restrict__ arA, const float* __restrict__ mrA,
    unsigned short* __restrict__ wtA, float* __restrict__ beA,
    const float* __restrict__ wB, const float* __restrict__ bB,
    const float* __restrict__ arB, const float* __restrict__ mrB,
    unsigned short* __restrict__ wtB, float* __restrict__ beB,
    const float* __restrict__ wC, const float* __restrict__ bC,
    const float* __restrict__ arC, const float* __restrict__ mrC,
    unsigned short* __restrict__ wtC, float* __restrict__ beC)
{
    int j = blockIdx.x / 384;
    int col = blockIdx.x % 384;
    const float *w, *b, *ar, *mr; unsigned short* wt; float* be;
    if (j == 0)      { w = wA; b = bA; ar = arA; mr = mrA; wt = wtA; be = beA; }
    else if (j == 1) { w = wB; b = bB; ar = arB; mr = mrB; wt = wtB; be = beB; }
    else             { w = wC; b = bC; ar = arC; mr = mrC; wt = wtC; be = beC; }
    int i = threadIdx.x;    // 0..127 (k-row)
    float acc, bacc;
    if (col >= 128 && col < 256) {
        acc = w[i * 384 + col];
        bacc = b[col];
    } else {
        const float* rel = (col < 128) ? ar : mr;
        int base = (col < 128) ? 0 : 256;
        int c = col - base;
        int h = c >> 6, jj = c & 63;
        acc = 0.0f; bacc = 0.0f;
        for (int d = 0; d < 64; ++d) {
            float rv = rel[(h * 64 + d) * 64 + jj];
            acc  = fmaf(w[i * 384 + base + h * 64 + d], rv, acc);
            bacc = fmaf(b[base + h * 64 + d], rv, bacc);
        }
    }
    wt[(size_t)col * 128 + i] = f2bf(acc);
    if (i == 0) be[col] = bacc;
}

struct Job {
    const unsigned short* WT;    // bf16 [128 cols][128 k] (pre-transposed)
    const float* bias;           // pre-offset, 128 window, f32
    const unsigned short* A;     // bf16 [M,128]
    const unsigned short* Xres;  // residual bf16 (EPI)
    const float* sgate;          // gate scalar (EPI)
    void* out;                   // [M,128] bf16 (opt. kv-interleaved) or [M,16] f32 (FINAL)
    int M;
    int omap;                    // 1: kv-interleaved [node][256]: c -> 8*(c>>2)+(c&3)+roleOff
    int roleOff;                 // 0 for k, 4 for v
};

// C[M,128] = op(A) @ WT^T + bias via bf16 MFMA. 64-row blocks (latency-bound regime, R10/R11).
// All operands pre-bf16 -> staging is pure copy. PRO: gelu(A). EPI: g*o+(1-g)*Xres (+RELU).
// FINAL: fused @wlT+bl -> out [M,16] f32.
// Frag layout (gfx950 16x16x32, HW-verified R4-R6): A/B lane&15=row/col, k=(lane>>4)*4+(e&3)+16*(e>>2);
// C/D row=(lane>>4)*4+reg, col=lane&15.
template<int PRO, int EPI, int RELU, int FINAL>
__global__ __launch_bounds__(256) void gemm64(
    Job j0, Job j1, Job j2, Job j3, Job j4, Job j5,
    const unsigned short* __restrict__ wlt, const float* __restrict__ blv)
{
    Job J;
    switch (blockIdx.y) {
        case 0: J = j0; break;
        case 1: J = j1; break;
        case 2: J = j2; break;
        case 3: J = j3; break;
        case 4: J = j4; break;
        default: J = j5; break;
    }
    const int row0 = blockIdx.x * 64;
    const int M = J.M;
    if (row0 >= M) return;

    constexpr int NSM = FINAL ? (64 * 132) : (64 * 36 + 128 * 36);
    __shared__ unsigned short sm[NSM];
    unsigned short* As = sm;               // [64][36]
    unsigned short* Bs = sm + 64 * 36;     // [128][36]

    const int t = threadIdx.x;
    const int lane = t & 63;
    const int w = t >> 6;
    const int l15 = lane & 15, l4 = lane >> 4;

    f32x4 acc[8];
    #pragma unroll
    for (int n = 0; n < 8; ++n) {
        float bv = J.bias[n * 16 + l15];
        acc[n] = f32x4{bv, bv, bv, bv};
    }

    union FR { uint2 u[2]; s16x8 v; };

    for (int kc = 0; kc < 4; ++kc) {
        const int k0 = kc * 32;
        ushort4 a_[2];
        #pragma unroll
        for (int i = 0; i < 2; ++i) {
            int idx = i * 256 + t;
            int r = idx >> 3, kq = idx & 7;
            int gr = row0 + r;
            ushort4 rv = {0, 0, 0, 0};
            if (gr < M) rv = *(const ushort4*)(J.A + (size_t)gr * 128 + k0 + kq * 4);
            if (PRO) {
                rv.x = f2bf(geluf(bf2f(rv.x)));
                rv.y = f2bf(geluf(bf2f(rv.y)));
                rv.z = f2bf(geluf(bf2f(rv.z)));
                rv.w = f2bf(geluf(bf2f(rv.w)));
            }
            a_[i] = rv;
        }
        ushort4 b_[4];
        #pragma unroll
        for (int i = 0; i < 4; ++i) {
            int idx = i * 256 + t;
            int c = idx >> 3, kq = idx & 7;
            b_[i] = *(const ushort4*)(J.WT + (size_t)c * 128 + k0 + kq * 4);
        }
        if (kc) __syncthreads();
        #pragma unroll
        for (int i = 0; i < 2; ++i) {
            int idx = i * 256 + t;
            int r = idx >> 3, kq = idx & 7;
            *(ushort4*)&As[r * 36 + kq * 4] = a_[i];
        }
        #pragma unroll
        for (int i = 0; i < 4; ++i) {
            int idx = i * 256 + t;
            int c = idx >> 3, kq = idx & 7;
            *(ushort4*)&Bs[c * 36 + kq * 4] = b_[i];
        }
        __syncthreads();

        FR af;
        {
            const unsigned short* p = &As[(w * 16 + l15) * 36 + l4 * 4];
            af.u[0] = *(const uint2*)p;
            af.u[1] = *(const uint2*)(p + 16);
        }
        #pragma unroll
        for (int n = 0; n < 8; ++n) {
            const unsigned short* p = &Bs[(n * 16 + l15) * 36 + l4 * 4];
            FR bfr;
            bfr.u[0] = *(const uint2*)p;
            bfr.u[1] = *(const uint2*)(p + 16);
            acc[n] = __builtin_amdgcn_mfma_f32_16x16x32_bf16(af.v, bfr.v, acc[n], 0, 0, 0);
        }
    }

    float g = 0.f, omg = 0.f;
    if (EPI == 1) { g = 1.0f / (1.0f + expf(-J.sgate[0])); omg = 1.0f - g; }

    if (FINAL) __syncthreads();   // all frag reads done before tile overwrites sm

    #pragma unroll
    for (int r = 0; r < 4; ++r) {
        int lr = w * 16 + l4 * 4 + r;
        int gr = row0 + lr;
        bool ok = gr < M;
        #pragma unroll
        for (int n = 0; n < 8; ++n) {
            float v = acc[n][r];
            if (EPI == 1) {
                float xv = ok ? bf2f(J.Xres[(size_t)gr * 128 + n * 16 + l15]) : 0.f;
                v = g * v + omg * xv;
                if (RELU) v = fmaxf(v, 0.0f);
            }
            if (FINAL) {
                sm[lr * 132 + n * 16 + l15] = f2bf(v);
            } else if (ok) {
                unsigned short hv = f2bf(v);
                int c = n * 16 + l15;
                if (J.omap)
                    ((unsigned short*)J.out)[(size_t)gr * 256 + ((c >> 2) << 3) + (c & 3) + J.roleOff] = hv;
                else
                    ((unsigned short*)J.out)[(size_t)gr * 128 + c] = hv;
            }
        }
    }

    if (FINAL) {
        // per-wave rows [w*16, w*16+16) @ wlT[16][128] + bl (same-wave LDS RAW; no barrier)
        f32x4 facc;
        float bv = blv[l15];
        facc = f32x4{bv, bv, bv, bv};
        #pragma unroll
        for (int kc2 = 0; kc2 < 4; ++kc2) {
            FR bfr, afr;
            #pragma unroll
            for (int h = 0; h < 2; ++h) {
                bfr.u[h] = *(const uint2*)&wlt[(size_t)l15 * 128 + kc2 * 32 + h * 16 + l4 * 4];
                afr.u[h] = *(const uint2*)&sm[(w * 16 + l15) * 132 + kc2 * 32 + h * 16 + l4 * 4];
            }
            facc = __builtin_amdgcn_mfma_f32_16x16x32_bf16(afr.v, bfr.v, facc, 0, 0, 0);
        }
        #pragma unroll
        for (int r = 0; r < 4; ++r) {
            int gr = row0 + w * 16 + l4 * 4 + r;
            if (gr < M) ((float*)J.out)[(size_t)gr * 16 + l15] = facc[r];
        }
    }
}

// per edge: slot = cnt[dst]++; bucket[dst*CAP+slot] = src
__global__ __launch_bounds__(256) void build_bucket(
    const int* __restrict__ src, const int* __restrict__ dst, int E,
    int* __restrict__ cnt, int* __restrict__ bucket)
{
    int e = blockIdx.x * 256 + threadIdx.x;
    if (e >= E) return;
    int d = dst[e];
    int slot = atomicAdd(&cnt[d], 1);
    if (slot < kCAP) bucket[(size_t)d * kCAP + slot] = src[e];
}

// Max-free single-pass segment softmax, TWO edges per wave iteration (R12 version —
// best measured; R13's DPP/uniform-load variant regressed, reverted).
// lanes 0-31 process edge 2i, lanes 32-63 edge 2i+1. lane&31 owns 4 row elems;
// 16-lane groups per head -> 4-step shfl reduce; final shfl_xor(32) merges halves.
// kv row groups-of-4 interleave -> one 16B load per lane per edge-pair.
__global__ __launch_bounds__(256) void fused_attn2(
    int nA, const int* __restrict__ cntA, const int* __restrict__ bucketA,
    const unsigned short* __restrict__ kvA, unsigned short* __restrict__ qoA,
    const float* __restrict__ prelA,
    int nB, const int* __restrict__ cntB, const int* __restrict__ bucketB,
    const unsigned short* __restrict__ kvB, unsigned short* __restrict__ qoB,
    const float* __restrict__ prelB)
{
    int wid = (blockIdx.x * 256 + threadIdx.x) >> 6;
    int lane = threadIdx.x & 63;
    const int* cnt; const int* bucket; const unsigned short* kvs;
    unsigned short* qo; const float* prel;
    if (wid < nA) {
        cnt = cntA; bucket = bucketA; kvs = kvA; qo = qoA; prel = prelA;
    } else {
        wid -= nA;
        if (wid >= nB) return;
        cnt = cntB; bucket = bucketB; kvs = kvB; qo = qoB; prel = prelB;
    }
    int deg = cnt[wid];
    if (deg > kCAP) deg = kCAP;
    const int l31 = lane & 31;
    int mys = (lane < deg) ? bucket[(size_t)wid * kCAP + lane] : 0;
    uint2 qv = *(const uint2*)(qo + (size_t)wid * 128 + l31 * 4);
    float q0 = bfLo(qv.x), q1 = bfHi(qv.x), q2 = bfLo(qv.y), q3 = bfHi(qv.y);
    float ph = prel[l31 >> 4] * 0.125f;   // / sqrt(64)

    float ss = 0.f, o0 = 0.f, o1 = 0.f, o2 = 0.f, o3 = 0.f;
    const int half = lane >> 5;     // 0: even edges, 1: odd edges
    const int nIt = (deg + 1) >> 1;
    for (int i = 0; i < nIt; ++i) {
        int idx = 2 * i + half;
        bool valid = idx < deg;
        int s = __shfl(mys, valid ? idx : 0);
        uint4 kv = *(const uint4*)(kvs + (size_t)s * 256 + l31 * 8);
        float p = q0 * bfLo(kv.x) + q1 * bfHi(kv.x) + q2 * bfLo(kv.y) + q3 * bfHi(kv.y);
        p += __shfl_xor(p, 1);
        p += __shfl_xor(p, 2);
        p += __shfl_xor(p, 4);
        p += __shfl_xor(p, 8);      // per-16-lane (=per-head) sum
        float wgt = valid ? __expf(p * ph) : 0.f;
        ss += wgt;
        o0 = fmaf(wgt, bfLo(kv.z), o0);
        o1 = fmaf(wgt, bfHi(kv.z), o1);
        o2 = fmaf(wgt, bfLo(kv.w), o2);
        o3 = fmaf(wgt, bfHi(kv.w), o3);
    }
    // merge even/odd partials across the two 32-lane halves
    ss += __shfl_xor(ss, 32);
    o0 += __shfl_xor(o0, 32);
    o1 += __shfl_xor(o1, 32);
    o2 += __shfl_xor(o2, 32);
    o3 += __shfl_xor(o3, 32);
    float rr = 1.0f / (ss + 1e-16f);
    if (lane < 32) {
        uint2 ov;
        ov.x = (unsigned)f2bf(o0 * rr) | ((unsigned)f2bf(o1 * rr) << 16);
        ov.y = (unsigned)f2bf(o2 * rr) | ((unsigned)f2bf(o3 * rr) << 16);
        *(uint2*)(qo + (size_t)wid * 128 + l31 * 4) = ov;
    }
}

extern "C" void kernel_launch(void* const* d_in, const int* in_sizes, int n_in,
                              void* d_out, int out_size, void* d_ws, size_t ws_size,
                              hipStream_t stream)
{
    const float* xc  = (const float*)d_in[0];
    const float* xp  = (const float*)d_in[1];
    const float* w1c = (const float*)d_in[2];
    const float* b1c = (const float*)d_in[3];
    const float* w1p = (const float*)d_in[4];
    const float* b1p = (const float*)d_in[5];
    const float* a1cp= (const float*)d_in[6];
    const float* m1cp= (const float*)d_in[7];
    const float* p1cp= (const float*)d_in[8];
    const float* a1pc= (const float*)d_in[9];
    const float* m1pc= (const float*)d_in[10];
    const float* p1pc= (const float*)d_in[11];
    const float* ow1c= (const float*)d_in[12];
    const float* ob1c= (const float*)d_in[13];
    const float* ow1p= (const float*)d_in[14];
    const float* ob1p= (const float*)d_in[15];
    const float* s1c = (const float*)d_in[16];
    const float* s1p = (const float*)d_in[17];
    const float* w2c = (const float*)d_in[18];
    const float* b2c = (const float*)d_in[19];
    const float* w2p = (const float*)d_in[20];
    const float* b2p = (const float*)d_in[21];
    const float* a2pc= (const float*)d_in[25];
    const float* m2pc= (const float*)d_in[26];
    const float* p2pc= (const float*)d_in[27];
    const float* ow2c= (const float*)d_in[28];
    const float* ob2c= (const float*)d_in[29];
    const float* s2c = (const float*)d_in[32];
    const float* wl  = (const float*)d_in[34];
    const float* bl  = (const float*)d_in[35];
    const int* ecp_s = (const int*)d_in[36];
    const int* ecp_d = (const int*)d_in[37];
    const int* epc_s = (const int*)d_in[38];
    const int* epc_d = (const int*)d_in[39];
    float* outF = (float*)d_out;
    (void)in_sizes; (void)n_in; (void)out_size; (void)ws_size;

    // ---- workspace layout (~188 MB) ----
    char* ws = (char*)d_ws;
    size_t off = 0;
    auto take = [&](size_t bytes) { char* p = ws + off; off += (bytes + 255) & ~(size_t)255; return p; };
    // R0: kvC interleaved bf16 [NC][256] (L1) -> hcb bf16 [NC][128] (from mix1 to end)
    char* R0 = take((size_t)kNC * 256 * 2);
    unsigned short* kvC = (unsigned short*)R0;
    unsigned short* hcb = (unsigned short*)R0;
    // R1: kvP interleaved bf16 [NP][256] (L1) -> reused for L2
    unsigned short* kvP = (unsigned short*)take((size_t)kNP * 256 * 2);
    // R2: q/attn-out bf16 [NT][128]
    unsigned short* qAll = (unsigned short*)take((size_t)kNT * 128 * 2);
    unsigned short* qC = qAll;
    unsigned short* qP = qAll + (size_t)kNC * 128;
    // R3: hp bf16
    unsigned short* hp = (unsigned short*)take((size_t)kNP * 128 * 2);
    // R4: buckets
    int* cntP = (int*)take((size_t)kNP * 4);
    int* cntC = (int*)take((size_t)kNC * 4);
    int* bucketP = (int*)take((size_t)kNP * kCAP * 4);
    int* bucketC = (int*)take((size_t)kNC * kCAP * 4);
    // R5: folded/converted weights, bf16 transposed [col][128]
    unsigned short* wecT  = (unsigned short*)take((size_t)384 * 128 * 2);
    unsigned short* wepT  = (unsigned short*)take((size_t)384 * 128 * 2);
    unsigned short* wep2T = (unsigned short*)take((size_t)384 * 128 * 2);
    unsigned short* ow1cT = (unsigned short*)take((size_t)128 * 128 * 2);
    unsigned short* ow1pT = (unsigned short*)take((size_t)128 * 128 * 2);
    unsigned short* ow2cT = (unsigned short*)take((size_t)128 * 128 * 2);
    unsigned short* w2cqT = (unsigned short*)take((size_t)128 * 128 * 2);
    unsigned short* wlT   = (unsigned short*)take((size_t)16 * 128 * 2);
    float* bec  = (float*)take((size_t)384 * 4);
    float* bep  = (float*)take((size_t)384 * 4);
    float* bep2 = (float*)take((size_t)384 * 4);
    // R6: bf16 copies of inputs
    unsigned short* xcb = (unsigned short*)take((size_t)kNC * 128 * 2);
    unsigned short* xpb = (unsigned short*)take((size_t)kNP * 128 * 2);

    auto cdiv = [](int a, int b) { return (a + b - 1) / b; };
    dim3 blk(256);
    const int gx = cdiv(kNC, 64);   // 1563
    const float* nf = nullptr;
    const unsigned short* nu = nullptr;

    // prep: buckets + dtype conversions + all weight folds (front-loaded, consolidated)
    hipMemsetAsync(cntP, 0, (size_t)kNP * 4, stream);
    hipMemsetAsync(cntC, 0, (size_t)kNC * 4, stream);
    hipLaunchKernelGGL(build_bucket, dim3(cdiv(kE1, 256)), blk, 0, stream, ecp_s, ecp_d, kE1, cntP, bucketP);
    hipLaunchKernelGGL(build_bucket, dim3(cdiv(kE2, 256)), blk, 0, stream, epc_s, epc_d, kE2, cntC, bucketC);
    hipLaunchKernelGGL(cvt_bf16, dim3(cdiv(kNC * 16, 256)), blk, 0, stream, xc, xcb, kNC * 16);
    hipLaunchKernelGGL(cvt_bf16, dim3(cdiv(kNP * 16, 256)), blk, 0, stream, xp, xpb, kNP * 16);
    hipLaunchKernelGGL(cvt_wT5, dim3(528), dim3(128), 0, stream,
                       ow1c, ow1p, ow2c, w2c + 128, wl,
                       ow1cT, ow1pT, ow2cT, w2cqT, wlT);
    hipLaunchKernelGGL(fold_all, dim3(1152), dim3(128), 0, stream,
                       w1c, b1c, a1cp, m1cp, wecT, bec,
                       w1p, b1p, a1pc, m1pc, wepT, bep,
                       w2p, b2p, a2pc, m2pc, wep2T, bep2);

    // ================= layer 1 =================
    Job jkC = { wecT + 0,       bec + 0,   xcb, nu, nf, (void*)kvC, kNC, 1, 0 };
    Job jqC = { wecT + 128*128, bec + 128, xcb, nu, nf, (void*)qC,  kNC, 0, 0 };
    Job jvC = { wecT + 256*128, bec + 256, xcb, nu, nf, (void*)kvC, kNC, 1, 4 };
    Job jkP = { wepT + 0,       bep + 0,   xpb, nu, nf, (void*)kvP, kNP, 1, 0 };
    Job jqP = { wepT + 128*128, bep + 128, xpb, nu, nf, (void*)qP,  kNP, 0, 0 };
    Job jvP = { wepT + 256*128, bep + 256, xpb, nu, nf, (void*)kvP, kNP, 1, 4 };
    hipLaunchKernelGGL((gemm64<0,0,0,0>), dim3(gx, 6), blk, 0, stream,
                       jkC, jqC, jvC, jkP, jqP, jvP, nu, nf);

    // both L1 attentions in one dispatch (reads q bf16, overwrites with out bf16)
    hipLaunchKernelGGL(fused_attn2, dim3(cdiv(kNP + kNC, 4)), blk, 0, stream,
                       kNP, cntP, bucketP, kvC, qP, p1cp,
                       kNC, cntC, bucketC, kvP, qC, p1pc);

    Job jmC = { ow1cT, ob1c, qC, xcb, s1c, (void*)hcb, kNC, 0, 0 };
    Job jmP = { ow1pT, ob1p, qP, xpb, s1p, (void*)hp,  kNP, 0, 0 };
    hipLaunchKernelGGL((gemm64<1,1,1,0>), dim3(gx, 2), blk, 0, stream,
                       jmC, jmP, jmC, jmC, jmC, jmC, nu, nf);

    // ================= layer 2 (customer outputs only -> pc edges only) =================
    Job jk2 = { wep2T + 0,       bep2 + 0,   hp,  nu, nf, (void*)kvP, kNP, 1, 0 };
    Job jv2 = { wep2T + 256*128, bep2 + 256, hp,  nu, nf, (void*)kvP, kNP, 1, 4 };
    Job jq2 = { w2cqT,           b2c + 128,  hcb, nu, nf, (void*)qC,  kNC, 0, 0 };
    hipLaunchKernelGGL((gemm64<0,0,0,0>), dim3(gx, 3), blk, 0, stream,
                       jk2, jv2, jq2, jk2, jk2, jk2, nu, nf);

    hipLaunchKernelGGL(fused_attn2, dim3(cdiv(kNC, 4)), blk, 0, stream,
                       kNC, cntC, bucketC, kvP, qC, p2pc,
                       0, cntC, bucketC, kvP, qC, p2pc);

    // mix2 + final projection fused: writes d_out [NC,16] directly
    Job jf = { ow2cT, ob2c, qC, hcb, s2c, (void*)outF, kNC, 0, 0 };
    hipLaunchKernelGGL((gemm64<1,1,0,1>), dim3(gx, 1), blk, 0, stream,
                       jf, jf, jf, jf, jf, jf, wlT, bl);
}

// Round 15
// 351.785 us; speedup vs baseline: 1.0789x; 1.0159x over previous
//
#include <hip/hip_runtime.h>

typedef __attribute__((ext_vector_type(8))) short s16x8;   // bf16x8 MFMA operand
typedef __attribute__((ext_vector_type(4))) float f32x4;   // MFMA accumulator

constexpr int kNC = 100000;
constexpr int kNP = 50000;
constexpr int kNT = kNC + kNP;
constexpr int kE1 = 300000;
constexpr int kE2 = 300000;
constexpr int kCAP = 32;   // max in-degree per node per edge type

__device__ __forceinline__ float geluf(float x) {
    return 0.5f * x * (1.0f + erff(x * 0.7071067811865475f));
}
__device__ __forceinline__ unsigned short f2bf(float f) {  // RTNE
    unsigned int u = __float_as_uint(f);
    u += 0x7fffu + ((u >> 16) & 1u);
    return (unsigned short)(u >> 16);
}
__device__ __forceinline__ float bf2f(unsigned short s) {
    return __uint_as_float(((unsigned int)s) << 16);
}
// packed-bf16 word -> two floats (hi is free: just mask; lo: shift)
__device__ __forceinline__ float bfLo(unsigned int w) { return __uint_as_float(w << 16); }
__device__ __forceinline__ float bfHi(unsigned int w) { return __uint_as_float(w & 0xffff0000u); }

// 16-lane rotate-reduce on the VALU pipe (DPP row_ror) — replaces 4 ds-pipe shfl_xor.
// After ror 1,2,4,8 every lane in each 16-lane row holds the row sum.
__device__ __forceinline__ float rowSum16(float s) {
    s += __int_as_float(__builtin_amdgcn_mov_dpp(__float_as_int(s), 0x121, 0xf, 0xf, false)); // row_ror:1
    s += __int_as_float(__builtin_amdgcn_mov_dpp(__float_as_int(s), 0x122, 0xf, 0xf, false)); // row_ror:2
    s += __int_as_float(__builtin_amdgcn_mov_dpp(__float_as_int(s), 0x124, 0xf, 0xf, false)); // row_ror:4
    s += __int_as_float(__builtin_amdgcn_mov_dpp(__float_as_int(s), 0x128, 0xf, 0xf, false)); // row_ror:8
    return s;
}

// f32 -> bf16 elementwise (8 elems/thread, vectorized)
__global__ __launch_bounds__(256) void cvt_bf16(
    const float* __restrict__ in, unsigned short* __restrict__ out, int n8)
{
    int i = blockIdx.x * 256 + threadIdx.x;
    if (i >= n8) return;
    float4 a = *(const float4*)(in + (size_t)i * 8);
    float4 b = *(const float4*)(in + (size_t)i * 8 + 4);
    ushort4 o0 = { f2bf(a.x), f2bf(a.y), f2bf(a.z), f2bf(a.w) };
    ushort4 o1 = { f2bf(b.x), f2bf(b.y), f2bf(b.z), f2bf(b.w) };
    *(ushort4*)(out + (size_t)i * 8) = o0;
    *(ushort4*)(out + (size_t)i * 8 + 4) = o1;
}

// 5 W->WT bf16 transpose-converts in ONE dispatch (grid 528)
__global__ __launch_bounds__(128) void cvt_wT5(
    const float* __restrict__ s0, const float* __restrict__ s1,
    const float* __restrict__ s2, const float* __restrict__ s3,
    const float* __restrict__ s4,
    unsigned short* __restrict__ d0, unsigned short* __restrict__ d1,
    unsigned short* __restrict__ d2, unsigned short* __restrict__ d3,
    unsigned short* __restrict__ d4)
{
    int b = blockIdx.x;
    const float* src; unsigned short* dst; int ldb; int c;
    if (b < 128)      { src = s0; dst = d0; ldb = 128; c = b; }
    else if (b < 256) { src = s1; dst = d1; ldb = 128; c = b - 128; }
    else if (b < 384) { src = s2; dst = d2; ldb = 128; c = b - 256; }
    else if (b < 512) { src = s3; dst = d3; ldb = 384; c = b - 384; }
    else              { src = s4; dst = d4; ldb = 16;  c = b - 512; }
    int r = threadIdx.x;    // 0..127 (k)
    dst[(size_t)c * 128 + r] = f2bf(src[(size_t)r * ldb + c]);
}

// All three kqv weight folds in ONE dispatch (grid 1152). Job j = blockIdx.x/384.
__global__ void fold_all(
    const float* __restrict__ wA, const float* __restrict__ bA,
    const float* __restrict__ arA, const float* __restrict__ mrA,
    unsigned short* __restrict__ wtA, float* __restrict__ beA,
    const float* __restrict__ wB, const float* __restrict__ bB,
    const float* __restrict__ arB, const float* __restrict__ mrB,
    unsigned short* __restrict__ wtB, float* __restrict__ beB,
    const float* __restrict__ wC, const float* __restrict__ bC,
    const float* __restrict__ arC, const float* __restrict__ mrC,
    unsigned short* __restrict__ wtC, float* __restrict__ beC)
{
    int j = blockIdx.x / 384;
    int col = blockIdx.x % 384;
    const float *w, *b, *ar, *mr; unsigned short* wt; float* be;
    if (j == 0)      { w = wA; b = bA; ar = arA; mr = mrA; wt = wtA; be = beA; }
    else if (j == 1) { w = wB; b = bB; ar = arB; mr = mrB; wt = wtB; be = beB; }
    else             { w = wC; b = bC; ar = arC; mr = mrC; wt = wtC; be = beC; }
    int i = threadIdx.x;    // 0..127 (k-row)
    float acc, bacc;
    if (col >= 128 && col < 256) {
        acc = w[i * 384 + col];
        bacc = b[col];
    } else {
        const float* rel = (col < 128) ? ar : mr;
        int base = (col < 128) ? 0 : 256;
        int c = col - base;
        int h = c >> 6, jj = c & 63;
        acc = 0.0f; bacc = 0.0f;
        for (int d = 0; d < 64; ++d) {
            float rv = rel[(h * 64 + d) * 64 + jj];
            acc  = fmaf(w[i * 384 + base + h * 64 + d], rv, acc);
            bacc = fmaf(b[base + h * 64 + d], rv, bacc);
        }
    }
    wt[(size_t)col * 128 + i] = f2bf(acc);
    if (i == 0) be[col] = bacc;
}

struct Job {
    const unsigned short* WT;    // bf16 [128 cols][128 k] (pre-transposed)
    const float* bias;           // pre-offset, 128 window, f32
    const unsigned short* A;     // bf16 [M,128]
    const unsigned short* Xres;  // residual bf16 (EPI)
    const float* sgate;          // gate scalar (EPI)
    void* out;                   // [M,128] bf16 (opt. kv-interleaved) or [M,16] f32 (FINAL)
    int M;
    int omap;                    // 1: kv-interleaved [node][256]: c -> 8*(c>>2)+(c&3)+roleOff
    int roleOff;                 // 0 for k, 4 for v
};

// C[M,128] = op(A) @ WT^T + bias via bf16 MFMA. 64-row blocks (latency-bound regime, R10/R11).
// All operands pre-bf16 -> staging is pure copy. PRO: gelu(A). EPI: g*o+(1-g)*Xres (+RELU).
// FINAL: fused @wlT+bl -> out [M,16] f32.
// Frag layout (gfx950 16x16x32, HW-verified R4-R6): A/B lane&15=row/col, k=(lane>>4)*4+(e&3)+16*(e>>2);
// C/D row=(lane>>4)*4+reg, col=lane&15.
template<int PRO, int EPI, int RELU, int FINAL>
__global__ __launch_bounds__(256) void gemm64(
    Job j0, Job j1, Job j2, Job j3, Job j4, Job j5,
    const unsigned short* __restrict__ wlt, const float* __restrict__ blv)
{
    Job J;
    switch (blockIdx.y) {
        case 0: J = j0; break;
        case 1: J = j1; break;
        case 2: J = j2; break;
        case 3: J = j3; break;
        case 4: J = j4; break;
        default: J = j5; break;
    }
    const int row0 = blockIdx.x * 64;
    const int M = J.M;
    if (row0 >= M) return;

    constexpr int NSM = FINAL ? (64 * 132) : (64 * 36 + 128 * 36);
    __shared__ unsigned short sm[NSM];
    unsigned short* As = sm;               // [64][36]
    unsigned short* Bs = sm + 64 * 36;     // [128][36]

    const int t = threadIdx.x;
    const int lane = t & 63;
    const int w = t >> 6;
    const int l15 = lane & 15, l4 = lane >> 4;

    f32x4 acc[8];
    #pragma unroll
    for (int n = 0; n < 8; ++n) {
        float bv = J.bias[n * 16 + l15];
        acc[n] = f32x4{bv, bv, bv, bv};
    }

    union FR { uint2 u[2]; s16x8 v; };

    for (int kc = 0; kc < 4; ++kc) {
        const int k0 = kc * 32;
        ushort4 a_[2];
        #pragma unroll
        for (int i = 0; i < 2; ++i) {
            int idx = i * 256 + t;
            int r = idx >> 3, kq = idx & 7;
            int gr = row0 + r;
            ushort4 rv = {0, 0, 0, 0};
            if (gr < M) rv = *(const ushort4*)(J.A + (size_t)gr * 128 + k0 + kq * 4);
            if (PRO) {
                rv.x = f2bf(geluf(bf2f(rv.x)));
                rv.y = f2bf(geluf(bf2f(rv.y)));
                rv.z = f2bf(geluf(bf2f(rv.z)));
                rv.w = f2bf(geluf(bf2f(rv.w)));
            }
            a_[i] = rv;
        }
        ushort4 b_[4];
        #pragma unroll
        for (int i = 0; i < 4; ++i) {
            int idx = i * 256 + t;
            int c = idx >> 3, kq = idx & 7;
            b_[i] = *(const ushort4*)(J.WT + (size_t)c * 128 + k0 + kq * 4);
        }
        if (kc) __syncthreads();
        #pragma unroll
        for (int i = 0; i < 2; ++i) {
            int idx = i * 256 + t;
            int r = idx >> 3, kq = idx & 7;
            *(ushort4*)&As[r * 36 + kq * 4] = a_[i];
        }
        #pragma unroll
        for (int i = 0; i < 4; ++i) {
            int idx = i * 256 + t;
            int c = idx >> 3, kq = idx & 7;
            *(ushort4*)&Bs[c * 36 + kq * 4] = b_[i];
        }
        __syncthreads();

        FR af;
        {
            const unsigned short* p = &As[(w * 16 + l15) * 36 + l4 * 4];
            af.u[0] = *(const uint2*)p;
            af.u[1] = *(const uint2*)(p + 16);
        }
        #pragma unroll
        for (int n = 0; n < 8; ++n) {
            const unsigned short* p = &Bs[(n * 16 + l15) * 36 + l4 * 4];
            FR bfr;
            bfr.u[0] = *(const uint2*)p;
            bfr.u[1] = *(const uint2*)(p + 16);
            acc[n] = __builtin_amdgcn_mfma_f32_16x16x32_bf16(af.v, bfr.v, acc[n], 0, 0, 0);
        }
    }

    float g = 0.f, omg = 0.f;
    if (EPI == 1) { g = 1.0f / (1.0f + expf(-J.sgate[0])); omg = 1.0f - g; }

    if (FINAL) __syncthreads();   // all frag reads done before tile overwrites sm

    #pragma unroll
    for (int r = 0; r < 4; ++r) {
        int lr = w * 16 + l4 * 4 + r;
        int gr = row0 + lr;
        bool ok = gr < M;
        #pragma unroll
        for (int n = 0; n < 8; ++n) {
            float v = acc[n][r];
            if (EPI == 1) {
                float xv = ok ? bf2f(J.Xres[(size_t)gr * 128 + n * 16 + l15]) : 0.f;
                v = g * v + omg * xv;
                if (RELU) v = fmaxf(v, 0.0f);
            }
            if (FINAL) {
                sm[lr * 132 + n * 16 + l15] = f2bf(v);
            } else if (ok) {
                unsigned short hv = f2bf(v);
                int c = n * 16 + l15;
                if (J.omap)
                    ((unsigned short*)J.out)[(size_t)gr * 256 + ((c >> 2) << 3) + (c & 3) + J.roleOff] = hv;
                else
                    ((unsigned short*)J.out)[(size_t)gr * 128 + c] = hv;
            }
        }
    }

    if (FINAL) {
        // per-wave rows [w*16, w*16+16) @ wlT[16][128] + bl (same-wave LDS RAW; no barrier)
        f32x4 facc;
        float bv = blv[l15];
        facc = f32x4{bv, bv, bv, bv};
        #pragma unroll
        for (int kc2 = 0; kc2 < 4; ++kc2) {
            FR bfr, afr;
            #pragma unroll
            for (int h = 0; h < 2; ++h) {
                bfr.u[h] = *(const uint2*)&wlt[(size_t)l15 * 128 + kc2 * 32 + h * 16 + l4 * 4];
                afr.u[h] = *(const uint2*)&sm[(w * 16 + l15) * 132 + kc2 * 32 + h * 16 + l4 * 4];
            }
            facc = __builtin_amdgcn_mfma_f32_16x16x32_bf16(afr.v, bfr.v, facc, 0, 0, 0);
        }
        #pragma unroll
        for (int r = 0; r < 4; ++r) {
            int gr = row0 + w * 16 + l4 * 4 + r;
            if (gr < M) ((float*)J.out)[(size_t)gr * 16 + l15] = facc[r];
        }
    }
}

// per edge: slot = cnt[dst]++; bucket[dst*CAP+slot] = src
__global__ __launch_bounds__(256) void build_bucket(
    const int* __restrict__ src, const int* __restrict__ dst, int E,
    int* __restrict__ cnt, int* __restrict__ bucket)
{
    int e = blockIdx.x * 256 + threadIdx.x;
    if (e >= E) return;
    int d = dst[e];
    int slot = atomicAdd(&cnt[d], 1);
    if (slot < kCAP) bucket[(size_t)d * kCAP + slot] = src[e];
}

// Max-free single-pass segment softmax, TWO edges per wave iteration.
// R12 structure (lane-held mys + __shfl addressing — proven best) with ONLY the
// per-head reduce moved to the VALU pipe (rowSum16 DPP) — isolating R13's two changes.
// lanes 0-31 process edge 2i, lanes 32-63 edge 2i+1. lane&31 owns 4 row elems;
// kv row groups-of-4 interleave -> one 16B load per lane per edge-pair.
__global__ __launch_bounds__(256) void fused_attn2(
    int nA, const int* __restrict__ cntA, const int* __restrict__ bucketA,
    const unsigned short* __restrict__ kvA, unsigned short* __restrict__ qoA,
    const float* __restrict__ prelA,
    int nB, const int* __restrict__ cntB, const int* __restrict__ bucketB,
    const unsigned short* __restrict__ kvB, unsigned short* __restrict__ qoB,
    const float* __restrict__ prelB)
{
    int wid = (blockIdx.x * 256 + threadIdx.x) >> 6;
    int lane = threadIdx.x & 63;
    const int* cnt; const int* bucket; const unsigned short* kvs;
    unsigned short* qo; const float* prel;
    if (wid < nA) {
        cnt = cntA; bucket = bucketA; kvs = kvA; qo = qoA; prel = prelA;
    } else {
        wid -= nA;
        if (wid >= nB) return;
        cnt = cntB; bucket = bucketB; kvs = kvB; qo = qoB; prel = prelB;
    }
    int deg = cnt[wid];
    if (deg > kCAP) deg = kCAP;
    const int l31 = lane & 31;
    int mys = (lane < deg) ? bucket[(size_t)wid * kCAP + lane] : 0;
    uint2 qv = *(const uint2*)(qo + (size_t)wid * 128 + l31 * 4);
    float q0 = bfLo(qv.x), q1 = bfHi(qv.x), q2 = bfLo(qv.y), q3 = bfHi(qv.y);
    float ph = prel[l31 >> 4] * 0.125f;   // / sqrt(64)

    float ss = 0.f, o0 = 0.f, o1 = 0.f, o2 = 0.f, o3 = 0.f;
    const int half = lane >> 5;     // 0: even edges, 1: odd edges
    const int nIt = (deg + 1) >> 1;
    for (int i = 0; i < nIt; ++i) {
        int idx = 2 * i + half;
        bool valid = idx < deg;
        int s = __shfl(mys, valid ? idx : 0);
        uint4 kv = *(const uint4*)(kvs + (size_t)s * 256 + l31 * 8);
        float p = q0 * bfLo(kv.x) + q1 * bfHi(kv.x) + q2 * bfLo(kv.y) + q3 * bfHi(kv.y);
        p = rowSum16(p);                          // per-head sum on the VALU pipe
        float wgt = valid ? __expf(p * ph) : 0.f;
        ss += wgt;
        o0 = fmaf(wgt, bfLo(kv.z), o0);
        o1 = fmaf(wgt, bfHi(kv.z), o1);
        o2 = fmaf(wgt, bfLo(kv.w), o2);
        o3 = fmaf(wgt, bfHi(kv.w), o3);
    }
    // merge even/odd partials across the two 32-lane halves
    ss += __shfl_xor(ss, 32);
    o0 += __shfl_xor(o0, 32);
    o1 += __shfl_xor(o1, 32);
    o2 += __shfl_xor(o2, 32);
    o3 += __shfl_xor(o3, 32);
    float rr = 1.0f / (ss + 1e-16f);
    if (lane < 32) {
        uint2 ov;
        ov.x = (unsigned)f2bf(o0 * rr) | ((unsigned)f2bf(o1 * rr) << 16);
        ov.y = (unsigned)f2bf(o2 * rr) | ((unsigned)f2bf(o3 * rr) << 16);
        *(uint2*)(qo + (size_t)wid * 128 + l31 * 4) = ov;
    }
}

extern "C" void kernel_launch(void* const* d_in, const int* in_sizes, int n_in,
                              void* d_out, int out_size, void* d_ws, size_t ws_size,
                              hipStream_t stream)
{
    const float* xc  = (const float*)d_in[0];
    const float* xp  = (const float*)d_in[1];
    const float* w1c = (const float*)d_in[2];
    const float* b1c = (const float*)d_in[3];
    const float* w1p = (const float*)d_in[4];
    const float* b1p = (const float*)d_in[5];
    const float* a1cp= (const float*)d_in[6];
    const float* m1cp= (const float*)d_in[7];
    const float* p1cp= (const float*)d_in[8];
    const float* a1pc= (const float*)d_in[9];
    const float* m1pc= (const float*)d_in[10];
    const float* p1pc= (const float*)d_in[11];
    const float* ow1c= (const float*)d_in[12];
    const float* ob1c= (const float*)d_in[13];
    const float* ow1p= (const float*)d_in[14];
    const float* ob1p= (const float*)d_in[15];
    const float* s1c = (const float*)d_in[16];
    const float* s1p = (const float*)d_in[17];
    const float* w2c = (const float*)d_in[18];
    const float* b2c = (const float*)d_in[19];
    const float* w2p = (const float*)d_in[20];
    const float* b2p = (const float*)d_in[21];
    const float* a2pc= (const float*)d_in[25];
    const float* m2pc= (const float*)d_in[26];
    const float* p2pc= (const float*)d_in[27];
    const float* ow2c= (const float*)d_in[28];
    const float* ob2c= (const float*)d_in[29];
    const float* s2c = (const float*)d_in[32];
    const float* wl  = (const float*)d_in[34];
    const float* bl  = (const float*)d_in[35];
    const int* ecp_s = (const int*)d_in[36];
    const int* ecp_d = (const int*)d_in[37];
    const int* epc_s = (const int*)d_in[38];
    const int* epc_d = (const int*)d_in[39];
    float* outF = (float*)d_out;
    (void)in_sizes; (void)n_in; (void)out_size; (void)ws_size;

    // ---- workspace layout (~188 MB) ----
    char* ws = (char*)d_ws;
    size_t off = 0;
    auto take = [&](size_t bytes) { char* p = ws + off; off += (bytes + 255) & ~(size_t)255; return p; };
    // R0: kvC interleaved bf16 [NC][256] (L1) -> hcb bf16 [NC][128] (from mix1 to end)
    char* R0 = take((size_t)kNC * 256 * 2);
    unsigned short* kvC = (unsigned short*)R0;
    unsigned short* hcb = (unsigned short*)R0;
    // R1: kvP interleaved bf16 [NP][256] (L1) -> reused for L2
    unsigned short* kvP = (unsigned short*)take((size_t)kNP * 256 * 2);
    // R2: q/attn-out bf16 [NT][128]
    unsigned short* qAll = (unsigned short*)take((size_t)kNT * 128 * 2);
    unsigned short* qC = qAll;
    unsigned short* qP = qAll + (size_t)kNC * 128;
    // R3: hp bf16
    unsigned short* hp = (unsigned short*)take((size_t)kNP * 128 * 2);
    // R4: buckets
    int* cntP = (int*)take((size_t)kNP * 4);
    int* cntC = (int*)take((size_t)kNC * 4);
    int* bucketP = (int*)take((size_t)kNP * kCAP * 4);
    int* bucketC = (int*)take((size_t)kNC * kCAP * 4);
    // R5: folded/converted weights, bf16 transposed [col][128]
    unsigned short* wecT  = (unsigned short*)take((size_t)384 * 128 * 2);
    unsigned short* wepT  = (unsigned short*)take((size_t)384 * 128 * 2);
    unsigned short* wep2T = (unsigned short*)take((size_t)384 * 128 * 2);
    unsigned short* ow1cT = (unsigned short*)take((size_t)128 * 128 * 2);
    unsigned short* ow1pT = (unsigned short*)take((size_t)128 * 128 * 2);
    unsigned short* ow2cT = (unsigned short*)take((size_t)128 * 128 * 2);
    unsigned short* w2cqT = (unsigned short*)take((size_t)128 * 128 * 2);
    unsigned short* wlT   = (unsigned short*)take((size_t)16 * 128 * 2);
    float* bec  = (float*)take((size_t)384 * 4);
    float* bep  = (float*)take((size_t)384 * 4);
    float* bep2 = (float*)take((size_t)384 * 4);
    // R6: bf16 copies of inputs
    unsigned short* xcb = (unsigned short*)take((size_t)kNC * 128 * 2);
    unsigned short* xpb = (unsigned short*)take((size_t)kNP * 128 * 2);

    auto cdiv = [](int a, int b) { return (a + b - 1) / b; };
    dim3 blk(256);
    const int gx = cdiv(kNC, 64);   // 1563
    const float* nf = nullptr;
    const unsigned short* nu = nullptr;

    // prep: buckets + dtype conversions + all weight folds (front-loaded, consolidated)
    hipMemsetAsync(cntP, 0, (size_t)kNP * 4, stream);
    hipMemsetAsync(cntC, 0, (size_t)kNC * 4, stream);
    hipLaunchKernelGGL(build_bucket, dim3(cdiv(kE1, 256)), blk, 0, stream, ecp_s, ecp_d, kE1, cntP, bucketP);
    hipLaunchKernelGGL(build_bucket, dim3(cdiv(kE2, 256)), blk, 0, stream, epc_s, epc_d, kE2, cntC, bucketC);
    hipLaunchKernelGGL(cvt_bf16, dim3(cdiv(kNC * 16, 256)), blk, 0, stream, xc, xcb, kNC * 16);
    hipLaunchKernelGGL(cvt_bf16, dim3(cdiv(kNP * 16, 256)), blk, 0, stream, xp, xpb, kNP * 16);
    hipLaunchKernelGGL(cvt_wT5, dim3(528), dim3(128), 0, stream,
                       ow1c, ow1p, ow2c, w2c + 128, wl,
                       ow1cT, ow1pT, ow2cT, w2cqT, wlT);
    hipLaunchKernelGGL(fold_all, dim3(1152), dim3(128), 0, stream,
                       w1c, b1c, a1cp, m1cp, wecT, bec,
                       w1p, b1p, a1pc, m1pc, wepT, bep,
                       w2p, b2p, a2pc, m2pc, wep2T, bep2);

    // ================= layer 1 =================
    Job jkC = { wecT + 0,       bec + 0,   xcb, nu, nf, (void*)kvC, kNC, 1, 0 };
    Job jqC = { wecT + 128*128, bec + 128, xcb, nu, nf, (void*)qC,  kNC, 0, 0 };
    Job jvC = { wecT + 256*128, bec + 256, xcb, nu, nf, (void*)kvC, kNC, 1, 4 };
    Job jkP = { wepT + 0,       bep + 0,   xpb, nu, nf, (void*)kvP, kNP, 1, 0 };
    Job jqP = { wepT + 128*128, bep + 128, xpb, nu, nf, (void*)qP,  kNP, 0, 0 };
    Job jvP = { wepT + 256*128, bep + 256, xpb, nu, nf, (void*)kvP, kNP, 1, 4 };
    hipLaunchKernelGGL((gemm64<0,0,0,0>), dim3(gx, 6), blk, 0, stream,
                       jkC, jqC, jvC, jkP, jqP, jvP, nu, nf);

    // both L1 attentions in one dispatch (reads q bf16, overwrites with out bf16)
    hipLaunchKernelGGL(fused_attn2, dim3(cdiv(kNP + kNC, 4)), blk, 0, stream,
                       kNP, cntP, bucketP, kvC, qP, p1cp,
                       kNC, cntC, bucketC, kvP, qC, p1pc);

    Job jmC = { ow1cT, ob1c, qC, xcb, s1c, (void*)hcb, kNC, 0, 0 };
    Job jmP = { ow1pT, ob1p, qP, xpb, s1p, (void*)hp,  kNP, 0, 0 };
    hipLaunchKernelGGL((gemm64<1,1,1,0>), dim3(gx, 2), blk, 0, stream,
                       jmC, jmP, jmC, jmC, jmC, jmC, nu, nf);

    // ================= layer 2 (customer outputs only -> pc edges only) =================
    Job jk2 = { wep2T + 0,       bep2 + 0,   hp,  nu, nf, (void*)kvP, kNP, 1, 0 };
    Job jv2 = { wep2T + 256*128, bep2 + 256, hp,  nu, nf, (void*)kvP, kNP, 1, 4 };
    Job jq2 = { w2cqT,           b2c + 128,  hcb, nu, nf, (void*)qC,  kNC, 0, 0 };
    hipLaunchKernelGGL((gemm64<0,0,0,0>), dim3(gx, 3), blk, 0, stream,
                       jk2, jv2, jq2, jk2, jk2, jk2, nu, nf);

    hipLaunchKernelGGL(fused_attn2, dim3(cdiv(kNC, 4)), blk, 0, stream,
                       kNC, cntC, bucketC, kvP, qC, p2pc,
                       0, cntC, bucketC, kvP, qC, p2pc);

    // mix2 + final projection fused: writes d_out [NC,16] directly
    Job jf = { ow2cT, ob2c, qC, hcb, s2c, (void*)outF, kNC, 0, 0 };
    hipLaunchKernelGGL((gemm64<1,1,0,1>), dim3(gx, 1), blk, 0, stream,
                       jf, jf, jf, jf, jf, jf, wlT, bl);
}